// Round 3
// baseline (489.973 us; speedup 1.0000x reference)
//
#include <hip/hip_runtime.h>
#include <hip/hip_bf16.h>

// Problem sizes (fixed)
#define Nn 32768   // nodes
#define Ee 131072  // edges
#define Gg 128     // graphs
#define Cc 4
#define Rr 2
#define Dd 128

using bf16 = __hip_bfloat16;
__device__ __forceinline__ float b2f(bf16 v){ return __bfloat162float(v); }
__device__ __forceinline__ bf16  f2b(float v){ return __float2bfloat16(v); }

// K1: x = bf16(x_feat@W_atom + b_atom); nm[rc,n] = softmax over c of (x@W_score)
// (scores computed from fp32 accumulators before the bf16 quantization of x)
__global__ void k_atom(const float* __restrict__ xf, const float* __restrict__ Wa,
                       const float* __restrict__ ba, const float* __restrict__ Wsc,
                       bf16* __restrict__ x, float* __restrict__ nm) {
  __shared__ float sxf[512];
  __shared__ float sx[1024];
  __shared__ float ss[64];
  int tid = threadIdx.x, n0 = blockIdx.x * 8;
  for (int j = 0; j < 4; ++j) sxf[tid + j*128] = xf[n0*64 + tid + j*128];
  __syncthreads();
  float acc[8];
  float bav = ba[tid];
  #pragma unroll
  for (int i = 0; i < 8; ++i) acc[i] = bav;
  for (int f = 0; f < 64; ++f) {
    float w = Wa[f*128 + tid];
    #pragma unroll
    for (int i = 0; i < 8; ++i) acc[i] += sxf[i*64 + f] * w;
  }
  #pragma unroll
  for (int i = 0; i < 8; ++i) { x[(n0+i)*128 + tid] = f2b(acc[i]); sx[i*128 + tid] = acc[i]; }
  __syncthreads();
  if (tid < 64) {
    int i = tid >> 3, col = tid & 7;
    float s = 0.f;
    for (int d = 0; d < 128; ++d) s += sx[i*128 + d] * Wsc[d*8 + col];
    ss[i*8 + col] = s;
  }
  __syncthreads();
  if (tid < 16) {
    int i = tid >> 1, k = tid & 1;
    float v0 = ss[i*8 + 0 + k], v1 = ss[i*8 + 2 + k], v2 = ss[i*8 + 4 + k], v3 = ss[i*8 + 6 + k];
    float mx = fmaxf(fmaxf(v0, v1), fmaxf(v2, v3));
    float e0 = expf(v0-mx), e1 = expf(v1-mx), e2 = expf(v2-mx), e3 = expf(v3-mx);
    float inv = 1.f / (e0+e1+e2+e3);
    int n = n0 + i;
    nm[(k*4+0)*Nn + n] = e0*inv;
    nm[(k*4+1)*Nn + n] = e1*inv;
    nm[(k*4+2)*Nn + n] = e2*inv;
    nm[(k*4+3)*Nn + n] = e3*inv;
  }
}

// K2: h = bf16(relu(x @ W_b2c))
__global__ void k_b2c(const bf16* __restrict__ x, const float* __restrict__ W,
                      bf16* __restrict__ h) {
  __shared__ float sa[1024];
  int tid = threadIdx.x, n0 = blockIdx.x*8;
  for (int j = 0; j < 8; ++j) sa[tid + j*128] = b2f(x[n0*128 + tid + j*128]);
  __syncthreads();
  float acc[8] = {0,0,0,0,0,0,0,0};
  for (int k = 0; k < 128; ++k) {
    float w = W[k*128 + tid];
    #pragma unroll
    for (int i = 0; i < 8; ++i) acc[i] += sa[i*128 + k] * w;
  }
  for (int i = 0; i < 8; ++i) h[(n0+i)*128 + tid] = f2b(fmaxf(acc[i], 0.f));
}

// K3: fused per-graph pooling (one block per graph, 256 threads):
//   num[rc,g,:] = sum_n nm*h[n] + sum_e nm[src]*nm[dst]^2*(h[src]+edge_emb)
//   den[rc,g]   = sum_n nm
//   abc[rc,g,:] = sum_n nm*x[n]
__global__ void k_pool(const bf16* __restrict__ x, const bf16* __restrict__ h,
                       const float* __restrict__ nm, const float* __restrict__ ea,
                       const float* __restrict__ We, const int* __restrict__ ei,
                       float* __restrict__ num, float* __restrict__ den,
                       float* __restrict__ abc) {
  __shared__ float snm[8*256];   // 8 KB, resident whole kernel
  __shared__ float sW[16*128];   // 8 KB
  __shared__ float sEA[256*16];  // 16 KB (per edge-chunk)
  __shared__ int   ssrc[256];    // 1 KB
  __shared__ float sw8[8*256];   // 8 KB
  __shared__ float scomb[16*128];// 8 KB
  int t = threadIdx.x, g = blockIdx.x;
  int half = t >> 7, d = t & 127;
  for (int j = t; j < 2048; j += 256) snm[j] = nm[(j>>8)*Nn + g*256 + (j&255)];
  for (int j = t; j < 2048; j += 256) sW[j] = We[j];
  __syncthreads();
  float aH[8] = {0}, aX[8] = {0};
  // node part: each half sums 128 of the graph's 256 nodes
  for (int pp = 0; pp < 128; ++pp) {
    int p = half*128 + pp;
    float hv = b2f(h[(g*256+p)*128 + d]);
    float xv = b2f(x[(g*256+p)*128 + d]);
    #pragma unroll
    for (int rc = 0; rc < 8; ++rc) { float w = snm[rc*256+p]; aH[rc] += w*hv; aX[rc] += w*xv; }
  }
  // edge part: 4 chunks of 256 edges
  for (int ch = 0; ch < 4; ++ch) {
    int e0 = g*1024 + ch*256;
    __syncthreads();  // prior chunk's reads done before restaging
    for (int j = t; j < 4096; j += 256) sEA[j] = ea[(size_t)e0*16 + j];
    {
      int e = e0 + t; int s = ei[e], dd = ei[Ee + e];
      ssrc[t] = s;
      #pragma unroll
      for (int rc = 0; rc < 8; ++rc) {
        float a = nm[rc*Nn + s], b = nm[rc*Nn + dd];
        sw8[rc*256 + t] = a*b*b;
      }
    }
    __syncthreads();
    for (int lee = 0; lee < 128; ++lee) {
      int le = half*128 + lee;
      float m = b2f(h[ssrc[le]*128 + d]);
      float eev = 0.f;
      #pragma unroll
      for (int j = 0; j < 16; ++j) eev += sEA[le*16 + j] * sW[j*128 + d];
      m += eev;
      #pragma unroll
      for (int rc = 0; rc < 8; ++rc) aH[rc] += sw8[rc*256 + le] * m;
    }
  }
  // combine the two halves and write out
  __syncthreads();
  #pragma unroll
  for (int rc = 0; rc < 8; ++rc) scomb[(half*8+rc)*128 + d] = aH[rc];
  __syncthreads();
  if (half == 0) {
    #pragma unroll
    for (int rc = 0; rc < 8; ++rc)
      num[(rc*Gg+g)*128 + d] = scomb[rc*128+d] + scomb[(8+rc)*128+d];
  }
  __syncthreads();
  #pragma unroll
  for (int rc = 0; rc < 8; ++rc) scomb[(half*8+rc)*128 + d] = aX[rc];
  __syncthreads();
  if (half == 0) {
    #pragma unroll
    for (int rc = 0; rc < 8; ++rc)
      abc[(rc*Gg+g)*128 + d] = scomb[rc*128+d] + scomb[(8+rc)*128+d];
  }
  if (t < 8) {
    float s = 0.f;
    for (int p = 0; p < 256; ++p) s += snm[t*256 + p];
    den[t*Gg + g] = s;
  }
}

// K4: centroid-pair weights Wcc per (r,g) + global max (detached-max norm).
__global__ void k_wcc(const float* __restrict__ nm, const int* __restrict__ ei,
                      float* __restrict__ wcc, unsigned int* __restrict__ maxbits) {
  __shared__ float red[20];
  int tid = threadIdx.x, g = blockIdx.x;
  if (tid < 20) red[tid] = 0.f;
  __syncthreads();
  float w[20];
  #pragma unroll
  for (int i = 0; i < 20; ++i) w[i] = 0.f;
  for (int q = 0; q < 4; ++q) {
    int e = g*1024 + tid*4 + q;
    int s = ei[e], d = ei[Ee + e];
    #pragma unroll
    for (int r = 0; r < 2; ++r) {
      float ps0 = nm[(r*4+0)*Nn+s], ps1 = nm[(r*4+1)*Nn+s], ps2 = nm[(r*4+2)*Nn+s], ps3 = nm[(r*4+3)*Nn+s];
      float pt0 = nm[(r*4+0)*Nn+d], pt1 = nm[(r*4+1)*Nn+d], pt2 = nm[(r*4+2)*Nn+d], pt3 = nm[(r*4+3)*Nn+d];
      w[r*10+0] += ps0*pt1; w[r*10+1] += ps0*pt2; w[r*10+2] += ps0*pt3;
      w[r*10+3] += ps1*pt2; w[r*10+4] += ps1*pt3; w[r*10+5] += ps2*pt3;
      w[r*10+6] += ps0*pt0; w[r*10+7] += ps1*pt1; w[r*10+8] += ps2*pt2; w[r*10+9] += ps3*pt3;
    }
  }
  #pragma unroll
  for (int i = 0; i < 20; ++i) atomicAdd(&red[i], w[i]);
  __syncthreads();
  if (tid < 32) {
    int r = tid >> 4, ij = tid & 15, i = ij >> 2, j = ij & 3;
    float v;
    if (i == j) v = 0.5f * red[r*10 + 6 + i];
    else { int a = i < j ? i : j, b = i < j ? j : i;
           int p = (a == 0) ? (b - 1) : (a == 1) ? (b + 1) : 5;
           v = red[r*10 + p]; }
    wcc[(r*Gg + g)*16 + ij] = v;
    atomicMax(maxbits, __float_as_uint(v));  // all v >= 0
  }
}

// K5: agg_bb[dst] += x[src] + edge_emb (edge_emb recomputed; global atomics)
__global__ void k_aggbb(const bf16* __restrict__ x, const float* __restrict__ ea,
                        const float* __restrict__ We, const int* __restrict__ ei,
                        float* __restrict__ aggbb) {
  __shared__ float sW[2048];
  __shared__ float sEA[256];
  __shared__ int ssrc[16], sdst[16];
  int tid = threadIdx.x;
  int e0 = blockIdx.x * 16;
  for (int j = 0; j < 16; ++j) sW[tid + j*128] = We[tid + j*128];
  sEA[tid]       = ea[e0*16 + tid];
  sEA[tid + 128] = ea[e0*16 + tid + 128];
  if (tid < 16) { ssrc[tid] = ei[e0 + tid]; sdst[tid] = ei[Ee + e0 + tid]; }
  __syncthreads();
  for (int i = 0; i < 16; ++i) {
    float v = b2f(x[ssrc[i]*128 + tid]);
    float eev = 0.f;
    #pragma unroll
    for (int j = 0; j < 16; ++j) eev += sEA[i*16 + j] * sW[j*128 + tid];
    atomicAdd(&aggbb[sdst[i]*128 + tid], v + eev);
  }
}

// K6: IN-PLACE: aggbb <- aggbb@W_bb + x@W_sb  (rows are block-exclusive;
// loaded to LDS before overwrite, so in-place is safe)
__global__ void k_bbsb(float* __restrict__ aggbb, const bf16* __restrict__ x,
                       const float* __restrict__ Wbb, const float* __restrict__ Wsb) {
  __shared__ float sa[1024], sb[1024];
  int tid = threadIdx.x, n0 = blockIdx.x*8;
  for (int j = 0; j < 8; ++j) {
    sa[tid + j*128] = aggbb[n0*128 + tid + j*128];
    sb[tid + j*128] = b2f(x[n0*128 + tid + j*128]);
  }
  __syncthreads();
  float acc[8] = {0};
  for (int k = 0; k < 128; ++k) {
    float w1 = Wbb[k*128 + tid], w2 = Wsb[k*128 + tid];
    #pragma unroll
    for (int i = 0; i < 8; ++i) acc[i] += sa[i*128 + k]*w1 + sb[i*128 + k]*w2;
  }
  for (int i = 0; i < 8; ++i) aggbb[(n0+i)*128 + tid] = acc[i];
}

// K7: cent_x = num/(den+1e-6); agg_cc = Wcc_norm @ cent_x;
//     h_cent = relu(agg_bc@W_bc + agg_cc@W_cc + cent_x@W_sc)
__global__ void k_hcent(const float* __restrict__ num, const float* __restrict__ den,
                        const float* __restrict__ abc, const float* __restrict__ wcc,
                        const unsigned int* __restrict__ maxbits,
                        const float* __restrict__ Wbc, const float* __restrict__ Wcc_,
                        const float* __restrict__ Wsc2, float* __restrict__ hcent) {
  __shared__ float scent[512], sbc[512], sccs[512], swcc[16];
  int tid = threadIdx.x, r = blockIdx.x >> 7, g = blockIdx.x & 127;
  float inv = 1.f / (__uint_as_float(*maxbits) + 1e-9f);
  if (tid < 16) swcc[tid] = wcc[(r*Gg + g)*16 + tid] * inv;
  for (int c = 0; c < 4; ++c) {
    int rc = r*4 + c;
    float dn = den[rc*Gg + g] + 1e-6f;
    scent[c*128 + tid] = num[(rc*Gg + g)*128 + tid] / dn;
    sbc[c*128 + tid]   = abc[(rc*Gg + g)*128 + tid];
  }
  __syncthreads();
  for (int i = 0; i < 4; ++i) {
    sccs[i*128 + tid] = swcc[i*4+0]*scent[tid]       + swcc[i*4+1]*scent[128 + tid]
                      + swcc[i*4+2]*scent[256 + tid] + swcc[i*4+3]*scent[384 + tid];
  }
  __syncthreads();
  for (int c = 0; c < 4; ++c) {
    float acc = 0.f;
    for (int k = 0; k < 128; ++k) {
      acc += sbc[c*128 + k]   * Wbc[k*128 + tid];
      acc += sccs[c*128 + k]  * Wcc_[k*128 + tid];
      acc += scent[c*128 + k] * Wsc2[k*128 + tid];
    }
    hcent[((r*Gg + g)*4 + c)*128 + tid] = fmaxf(acc, 0.f);
  }
}

// K8: agg_cb = sum_c nm*h_cent; h_base = relu(bbsb + agg_cb@W_cb);
// mean over r, then per-graph sum accumulated into gsum[G,D] (atomics)
__global__ void k_hbase(const float* __restrict__ bbsb, const float* __restrict__ nm,
                        const float* __restrict__ hcent, const float* __restrict__ Wcb,
                        float* __restrict__ gsum) {
  __shared__ float shc[512], scb[1024], snm[32];
  int tid = threadIdx.x, n0 = blockIdx.x*8, g = n0 >> 8;
  float bb[8], msum[8];
  #pragma unroll
  for (int i = 0; i < 8; ++i) { bb[i] = bbsb[(n0+i)*128 + tid]; msum[i] = 0.f; }
  for (int r = 0; r < 2; ++r) {
    for (int c = 0; c < 4; ++c) shc[c*128 + tid] = hcent[((r*Gg + g)*4 + c)*128 + tid];
    if (tid < 32) { int c = tid >> 3, i = tid & 7; snm[tid] = nm[(r*4 + c)*Nn + n0 + i]; }
    __syncthreads();
    #pragma unroll
    for (int i = 0; i < 8; ++i) {
      scb[i*128 + tid] = snm[i]*shc[tid] + snm[8+i]*shc[128 + tid]
                       + snm[16+i]*shc[256 + tid] + snm[24+i]*shc[384 + tid];
    }
    __syncthreads();
    float acc[8] = {0};
    for (int k = 0; k < 128; ++k) {
      float w = Wcb[k*128 + tid];
      #pragma unroll
      for (int i = 0; i < 8; ++i) acc[i] += scb[i*128 + k] * w;
    }
    #pragma unroll
    for (int i = 0; i < 8; ++i) msum[i] += 0.5f * fmaxf(bb[i] + acc[i], 0.f);
    __syncthreads();
  }
  float tot = 0.f;
  #pragma unroll
  for (int i = 0; i < 8; ++i) tot += msum[i];
  atomicAdd(&gsum[g*128 + tid], tot);
}

// K9: graph mean + W_inter + W_out head
__global__ void k_out(const float* __restrict__ gsum, const float* __restrict__ Wint,
                      const float* __restrict__ bint, const float* __restrict__ Wout,
                      const float* __restrict__ bout, float* __restrict__ out) {
  __shared__ float ss[128], sge[128];
  int tid = threadIdx.x, g = blockIdx.x;
  ss[tid] = gsum[g*128 + tid] * (1.f/256.f);
  __syncthreads();
  float ge = bint[tid];
  for (int k = 0; k < 128; ++k) ge += ss[k] * Wint[k*128 + tid];
  sge[tid] = ge;
  __syncthreads();
  if (tid < 10) {
    float o = bout[tid];
    for (int d = 0; d < 128; ++d) o += sge[d] * Wout[d*10 + tid];
    out[g*10 + tid] = o;
  }
}

extern "C" void kernel_launch(void* const* d_in, const int* in_sizes, int n_in,
                              void* d_out, int out_size, void* d_ws, size_t ws_size,
                              hipStream_t stream) {
  const float* xf   = (const float*)d_in[0];
  const float* ea   = (const float*)d_in[1];
  const float* Wa   = (const float*)d_in[2];
  const float* ba   = (const float*)d_in[3];
  const float* Wsc  = (const float*)d_in[4];
  const float* We   = (const float*)d_in[5];
  const float* Wb2c = (const float*)d_in[6];
  const float* Wbb  = (const float*)d_in[7];
  const float* Wbc  = (const float*)d_in[8];
  const float* Wcb  = (const float*)d_in[9];
  const float* WccW = (const float*)d_in[10];
  const float* Wsb  = (const float*)d_in[11];
  const float* Wsc2 = (const float*)d_in[12];
  const float* Wint = (const float*)d_in[13];
  const float* bint = (const float*)d_in[14];
  const float* Wout = (const float*)d_in[15];
  const float* bout = (const float*)d_in[16];
  const int*   ei   = (const int*)d_in[17];

  // Workspace layout (float offsets); total = 9,065,536 floats = 34.6 MB
  float* ws    = (float*)d_ws;
  bf16*  x     = (bf16*)(ws);                        // [N,D] bf16  (2,097,152 f)
  bf16*  h     = (bf16*)(ws + 2097152);              // [N,D] bf16  (2,097,152 f)
  float* nm    = ws + 4194304;                       // [8,N]       (262,144 f)
  float* num   = ws + 4456448;                       // [8,G,D]     (131,072 f)
  float* den   = ws + 4587520;                       // [8,G]       (1,024 f)
  float* abc   = ws + 4588544;                       // [8,G,D]     (131,072 f)
  float* hcent = ws + 4719616;                       // [R,G,C,D]   (131,072 f)
  float* wcc   = ws + 4850688;                       // [R,G,16]    (4,096 f)
  float* aggbb = ws + 4854784;                       // [N,D] fp32  (4,194,304 f) -> becomes bbsb in-place
  float* gsum  = ws + 9049088;                       // [G,D]       (16,384 f)
  unsigned int* maxbits = (unsigned int*)(ws + 9065472); // (64 f)

  // zero the accumulated regions (aggbb, gsum, maxbits are contiguous)
  hipMemsetAsync(aggbb, 0, (4194304 + 16384 + 64) * sizeof(float), stream);

  k_atom <<<Nn/8, 128, 0, stream>>>(xf, Wa, ba, Wsc, x, nm);
  k_b2c  <<<Nn/8, 128, 0, stream>>>(x, Wb2c, h);
  k_pool <<<Gg,   256, 0, stream>>>(x, h, nm, ea, We, ei, num, den, abc);
  k_wcc  <<<Gg,   256, 0, stream>>>(nm, ei, wcc, maxbits);
  k_aggbb<<<Ee/16,128, 0, stream>>>(x, ea, We, ei, aggbb);
  k_bbsb <<<Nn/8, 128, 0, stream>>>(aggbb, x, Wbb, Wsb);
  k_hcent<<<Rr*Gg,128, 0, stream>>>(num, den, abc, wcc, maxbits, Wbc, WccW, Wsc2, hcent);
  k_hbase<<<Nn/8, 128, 0, stream>>>(aggbb, nm, hcent, Wcb, gsum);
  k_out  <<<Gg,   128, 0, stream>>>(gsum, Wint, bint, Wout, bout, (float*)d_out);
}